// Round 2
// baseline (192.706 us; speedup 1.0000x reference)
//
#include <hip/hip_runtime.h>
#include <hip/hip_fp16.h>

// score[e] = relu(h[src[e]]@W1s + h[dst[e]]@W1d + b1) @ W2 + b2
// N_NODES=100000, N_EDGES=1600000, H=64.
// Phase 1: per-node P = h@W1s + b1, Q = h@W1d (fp16, L2/L3-resident).
// Phase 2: per-edge gather P[src],Q[dst] + relu + dot(w2).

#define HF 64

// ---------------- Phase 1: per-node projection ----------------
// 128 threads: thread ct owns output column (ct&63) of P (ct<64) or Q (ct>=64).
// W1 column in 64 VGPRs. 4 nodes per iteration for ILP: 16 independent
// accumulator chains, 64 independent wave-uniform loads in flight.
__global__ __launch_bounds__(128) void node_proj_kernel(
    const float* __restrict__ h, const float* __restrict__ W1,
    const float* __restrict__ b1, __half* __restrict__ P,
    __half* __restrict__ Q, int n_nodes)
{
    const int ct  = threadIdx.x;       // 0..127
    const int c   = ct & 63;
    const bool isQ = ct >= 64;

    float wc[64];
    const float* wbase = W1 + (isQ ? (64 * 64) : 0) + c;
    #pragma unroll
    for (int k = 0; k < 64; ++k) wc[k] = wbase[k * 64];

    const float bias = isQ ? 0.0f : b1[c];
    __half* outbase = (isQ ? Q : P) + c;

    const int stride = gridDim.x * 4;
    for (int n0 = blockIdx.x * 4; n0 < n_nodes; n0 += stride) {
        if (n0 + 4 <= n_nodes) {
            const float4* r0 = (const float4*)(h + (size_t)(n0 + 0) * HF);
            const float4* r1 = (const float4*)(h + (size_t)(n0 + 1) * HF);
            const float4* r2 = (const float4*)(h + (size_t)(n0 + 2) * HF);
            const float4* r3 = (const float4*)(h + (size_t)(n0 + 3) * HF);
            float a0x=0.f,a0y=0.f,a0z=0.f,a0w=0.f;
            float a1x=0.f,a1y=0.f,a1z=0.f,a1w=0.f;
            float a2x=0.f,a2y=0.f,a2z=0.f,a2w=0.f;
            float a3x=0.f,a3y=0.f,a3z=0.f,a3w=0.f;
            #pragma unroll
            for (int k4 = 0; k4 < 16; ++k4) {
                float4 v0 = r0[k4];
                float4 v1 = r1[k4];
                float4 v2 = r2[k4];
                float4 v3 = r3[k4];
                const float w0 = wc[k4*4+0], w1 = wc[k4*4+1];
                const float w2 = wc[k4*4+2], w3 = wc[k4*4+3];
                a0x = fmaf(v0.x, w0, a0x); a0y = fmaf(v0.y, w1, a0y);
                a0z = fmaf(v0.z, w2, a0z); a0w = fmaf(v0.w, w3, a0w);
                a1x = fmaf(v1.x, w0, a1x); a1y = fmaf(v1.y, w1, a1y);
                a1z = fmaf(v1.z, w2, a1z); a1w = fmaf(v1.w, w3, a1w);
                a2x = fmaf(v2.x, w0, a2x); a2y = fmaf(v2.y, w1, a2y);
                a2z = fmaf(v2.z, w2, a2z); a2w = fmaf(v2.w, w3, a2w);
                a3x = fmaf(v3.x, w0, a3x); a3y = fmaf(v3.y, w1, a3y);
                a3z = fmaf(v3.z, w2, a3z); a3w = fmaf(v3.w, w3, a3w);
            }
            outbase[(size_t)(n0 + 0) * HF] = __float2half((a0x + a0y) + (a0z + a0w) + bias);
            outbase[(size_t)(n0 + 1) * HF] = __float2half((a1x + a1y) + (a1z + a1w) + bias);
            outbase[(size_t)(n0 + 2) * HF] = __float2half((a2x + a2y) + (a2z + a2w) + bias);
            outbase[(size_t)(n0 + 3) * HF] = __float2half((a3x + a3y) + (a3z + a3w) + bias);
        } else {
            for (int n = n0; n < n_nodes; ++n) {
                const float4* hv = (const float4*)(h + (size_t)n * HF);
                float ax=0.f, ay=0.f, az=0.f, aw=0.f;
                #pragma unroll
                for (int k4 = 0; k4 < 16; ++k4) {
                    float4 v = hv[k4];
                    ax = fmaf(v.x, wc[k4*4+0], ax);
                    ay = fmaf(v.y, wc[k4*4+1], ay);
                    az = fmaf(v.z, wc[k4*4+2], az);
                    aw = fmaf(v.w, wc[k4*4+3], aw);
                }
                outbase[(size_t)n * HF] = __float2half((ax + ay) + (az + aw) + bias);
            }
        }
    }
}

// ---------------- Phase 2: per-edge score ----------------
// 8 lanes per edge; lane sub owns features sub*8..sub*8+7 (one 16B load from
// P[src] + one from Q[dst]). 2 edges per iteration for memory-level
// parallelism (4 outstanding gathers). Butterfly-reduce over the 8-lane group.
__global__ __launch_bounds__(256) void edge_score_kernel(
    const __half* __restrict__ P, const __half* __restrict__ Q,
    const int* __restrict__ src, const int* __restrict__ dst,
    const float* __restrict__ W2, const float* __restrict__ b2,
    float* __restrict__ out, int n_edges)
{
    const int tid      = blockIdx.x * blockDim.x + threadIdx.x;
    const int sub      = tid & 7;
    const int group    = tid >> 3;
    const int n_groups = (gridDim.x * blockDim.x) >> 3;
    const int j0       = sub * 8;

    float w2v[8];
    #pragma unroll
    for (int i = 0; i < 8; ++i) w2v[i] = W2[j0 + i];
    const float bias2 = b2[0];

    for (int e = group; e < n_edges; e += 2 * n_groups) {
        const int ep = e + n_groups;
        const bool has2 = ep < n_edges;

        const int sa = src[e];
        const int da = dst[e];
        const int sb = has2 ? src[ep] : sa;
        const int db = has2 ? dst[ep] : da;

        const uint4 pa = *(const uint4*)(P + (size_t)sa * HF + j0);
        const uint4 qa = *(const uint4*)(Q + (size_t)da * HF + j0);
        const uint4 pb = *(const uint4*)(P + (size_t)sb * HF + j0);
        const uint4 qb = *(const uint4*)(Q + (size_t)db * HF + j0);

        const __half2* pha = (const __half2*)&pa;
        const __half2* qha = (const __half2*)&qa;
        const __half2* phb = (const __half2*)&pb;
        const __half2* qhb = (const __half2*)&qb;

        float acca = 0.f, accb = 0.f;
        #pragma unroll
        for (int i = 0; i < 4; ++i) {
            float2 pfa = __half22float2(pha[i]);
            float2 qfa = __half22float2(qha[i]);
            float2 pfb = __half22float2(phb[i]);
            float2 qfb = __half22float2(qhb[i]);
            float xa0 = fmaxf(pfa.x + qfa.x, 0.f);
            float xa1 = fmaxf(pfa.y + qfa.y, 0.f);
            float xb0 = fmaxf(pfb.x + qfb.x, 0.f);
            float xb1 = fmaxf(pfb.y + qfb.y, 0.f);
            acca = fmaf(xa0, w2v[i*2+0], acca);
            acca = fmaf(xa1, w2v[i*2+1], acca);
            accb = fmaf(xb0, w2v[i*2+0], accb);
            accb = fmaf(xb1, w2v[i*2+1], accb);
        }
        acca += __shfl_xor(acca, 4, 8);
        acca += __shfl_xor(acca, 2, 8);
        acca += __shfl_xor(acca, 1, 8);
        accb += __shfl_xor(accb, 4, 8);
        accb += __shfl_xor(accb, 2, 8);
        accb += __shfl_xor(accb, 1, 8);
        if (sub == 0) {
            __builtin_nontemporal_store(acca + bias2, &out[e]);
            if (has2) __builtin_nontemporal_store(accb + bias2, &out[ep]);
        }
    }
}

extern "C" void kernel_launch(void* const* d_in, const int* in_sizes, int n_in,
                              void* d_out, int out_size, void* d_ws, size_t ws_size,
                              hipStream_t stream) {
    const float* h   = (const float*)d_in[0];
    const int*   src = (const int*)d_in[1];
    const int*   dst = (const int*)d_in[2];
    const float* W1  = (const float*)d_in[3];
    const float* b1  = (const float*)d_in[4];
    const float* W2  = (const float*)d_in[5];
    const float* b2  = (const float*)d_in[6];
    float* out = (float*)d_out;

    const int n_nodes = in_sizes[0] / HF;
    const int n_edges = in_sizes[1];

    __half* P = (__half*)d_ws;
    __half* Q = P + (size_t)n_nodes * HF;

    node_proj_kernel<<<2048, 128, 0, stream>>>(h, W1, b1, P, Q, n_nodes);
    edge_score_kernel<<<4096, 256, 0, stream>>>(P, Q, src, dst, W2, b2, out, n_edges);
}

// Round 3
// 171.882 us; speedup vs baseline: 1.1212x; 1.1212x over previous
//
#include <hip/hip_runtime.h>
#include <hip/hip_fp16.h>

// score[e] = relu(h[src[e]]@W1s + h[dst[e]]@W1d + b1) @ W2 + b2
// N_NODES=100000, N_EDGES=1600000, H=64.
// Phase 1: per-node P = h@W1s + b1, Q = h@W1d (fp16, 25.6 MB, L2/L3-resident).
//   lane = node, W1 staged in LDS (wave-uniform broadcast reads), per-lane
//   coalesced-ish float4 h loads -> high bytes-in-flight, high VALU duty.
// Phase 2: per-edge gather P[src],Q[dst] (one 128B line each) + relu + dot(w2).
//   one-shot blocks, 4 edges per 8-lane group, 8 independent gathers in flight.

#define HF 64

// ---------------- Phase 1: per-node projection ----------------
__global__ __launch_bounds__(256) void node_proj_kernel(
    const float* __restrict__ h, const float* __restrict__ W1,
    const float* __restrict__ b1, __half* __restrict__ P,
    __half* __restrict__ Q, int n_nodes)
{
    // Wlds[k][cc]: cc<64 -> P column cc (weights W1[k][cc]);
    //             cc>=64 -> Q column cc-64 (weights W1[64+k][cc-64]).
    __shared__ float Wlds[64][128];
    __shared__ float blds[128];

    const int tid = threadIdx.x;
    for (int i = tid; i < 128 * 64; i += 256) {
        const int r = i >> 6, c0 = i & 63;
        Wlds[r & 63][c0 + ((r >= 64) ? 64 : 0)] = W1[i];
    }
    if (tid < 128) blds[tid] = (tid < 64) ? b1[tid] : 0.0f;
    __syncthreads();

    const int wave = tid >> 6;     // 0..3 -> column quarter
    const int lane = tid & 63;     // -> node within the 64-node tile
    const int cq   = wave * 32;    // starting cc
    __half* const outPQ = (cq < 64) ? P : Q;
    const int ccol = cq & 63;

    for (int n0 = blockIdx.x * 64; n0 < n_nodes; n0 += gridDim.x * 64) {
        const int n = n0 + lane;
        const bool valid = (n < n_nodes);
        const int nc = valid ? n : (n_nodes - 1);
        const float4* hrow = (const float4*)(h + (size_t)nc * HF);

        float acc[32];
        #pragma unroll
        for (int c = 0; c < 32; ++c) acc[c] = 0.f;

        #pragma unroll
        for (int k4 = 0; k4 < 16; ++k4) {
            const float4 v = hrow[k4];
            const int k = k4 * 4;
            #pragma unroll
            for (int cg = 0; cg < 8; ++cg) {
                const float4 w0 = *(const float4*)&Wlds[k + 0][cq + cg * 4];
                const float4 w1 = *(const float4*)&Wlds[k + 1][cq + cg * 4];
                const float4 w2 = *(const float4*)&Wlds[k + 2][cq + cg * 4];
                const float4 w3 = *(const float4*)&Wlds[k + 3][cq + cg * 4];
                float* a = &acc[cg * 4];
                a[0] = fmaf(v.x, w0.x, a[0]);
                a[1] = fmaf(v.x, w0.y, a[1]);
                a[2] = fmaf(v.x, w0.z, a[2]);
                a[3] = fmaf(v.x, w0.w, a[3]);
                a[0] = fmaf(v.y, w1.x, a[0]);
                a[1] = fmaf(v.y, w1.y, a[1]);
                a[2] = fmaf(v.y, w1.z, a[2]);
                a[3] = fmaf(v.y, w1.w, a[3]);
                a[0] = fmaf(v.z, w2.x, a[0]);
                a[1] = fmaf(v.z, w2.y, a[1]);
                a[2] = fmaf(v.z, w2.z, a[2]);
                a[3] = fmaf(v.z, w2.w, a[3]);
                a[0] = fmaf(v.w, w3.x, a[0]);
                a[1] = fmaf(v.w, w3.y, a[1]);
                a[2] = fmaf(v.w, w3.z, a[2]);
                a[3] = fmaf(v.w, w3.w, a[3]);
            }
        }

        if (valid) {
            __half* base = outPQ + (size_t)n * HF + ccol;
            #pragma unroll
            for (int g = 0; g < 4; ++g) {
                union { uint4 u; __half2 hh[4]; } pk;
                #pragma unroll
                for (int j = 0; j < 4; ++j) {
                    const float x0 = acc[g * 8 + j * 2 + 0] + blds[cq + g * 8 + j * 2 + 0];
                    const float x1 = acc[g * 8 + j * 2 + 1] + blds[cq + g * 8 + j * 2 + 1];
                    pk.hh[j] = __floats2half2_rn(x0, x1);
                }
                *(uint4*)(base + g * 8) = pk.u;
            }
        }
    }
}

// ---------------- Phase 2: per-edge score ----------------
__device__ __forceinline__ float dot8_relu(uint4 pv, uint4 qv, float4 wa, float4 wb) {
    const __half2* ph = (const __half2*)&pv;
    const __half2* qh = (const __half2*)&qv;
    const float2 p0 = __half22float2(ph[0]), q0 = __half22float2(qh[0]);
    const float2 p1 = __half22float2(ph[1]), q1 = __half22float2(qh[1]);
    const float2 p2 = __half22float2(ph[2]), q2 = __half22float2(qh[2]);
    const float2 p3 = __half22float2(ph[3]), q3 = __half22float2(qh[3]);
    float acc = 0.f;
    acc = fmaf(fmaxf(p0.x + q0.x, 0.f), wa.x, acc);
    acc = fmaf(fmaxf(p0.y + q0.y, 0.f), wa.y, acc);
    acc = fmaf(fmaxf(p1.x + q1.x, 0.f), wa.z, acc);
    acc = fmaf(fmaxf(p1.y + q1.y, 0.f), wa.w, acc);
    acc = fmaf(fmaxf(p2.x + q2.x, 0.f), wb.x, acc);
    acc = fmaf(fmaxf(p2.y + q2.y, 0.f), wb.y, acc);
    acc = fmaf(fmaxf(p3.x + q3.x, 0.f), wb.z, acc);
    acc = fmaf(fmaxf(p3.y + q3.y, 0.f), wb.w, acc);
    return acc;
}

__global__ __launch_bounds__(256) void edge_score_kernel(
    const __half* __restrict__ P, const __half* __restrict__ Q,
    const int* __restrict__ src, const int* __restrict__ dst,
    const float* __restrict__ W2, const float* __restrict__ b2,
    float* __restrict__ out, int n_edges)
{
    const int tid   = blockIdx.x * 256 + threadIdx.x;
    const int sub   = threadIdx.x & 7;
    const int group = tid >> 3;
    const int j0    = sub * 8;
    const int e0    = group * 4;
    if (e0 >= n_edges) return;

    const float4 w2a = *(const float4*)(W2 + j0);
    const float4 w2b = *(const float4*)(W2 + j0 + 4);
    const float bias2 = b2[0];

    if (e0 + 4 <= n_edges) {
        // broadcast index loads (same address across the 8-lane group)
        const int4 s4 = *(const int4*)(src + e0);
        const int4 d4 = *(const int4*)(dst + e0);
        // 8 independent 16B gathers (each group's 8 lanes cover one 128B row)
        const uint4 pa = *(const uint4*)(P + (size_t)s4.x * HF + j0);
        const uint4 pb = *(const uint4*)(P + (size_t)s4.y * HF + j0);
        const uint4 pc = *(const uint4*)(P + (size_t)s4.z * HF + j0);
        const uint4 pd = *(const uint4*)(P + (size_t)s4.w * HF + j0);
        const uint4 qa = *(const uint4*)(Q + (size_t)d4.x * HF + j0);
        const uint4 qb = *(const uint4*)(Q + (size_t)d4.y * HF + j0);
        const uint4 qc = *(const uint4*)(Q + (size_t)d4.z * HF + j0);
        const uint4 qd = *(const uint4*)(Q + (size_t)d4.w * HF + j0);

        float sc0 = dot8_relu(pa, qa, w2a, w2b);
        float sc1 = dot8_relu(pb, qb, w2a, w2b);
        float sc2 = dot8_relu(pc, qc, w2a, w2b);
        float sc3 = dot8_relu(pd, qd, w2a, w2b);

        sc0 += __shfl_xor(sc0, 4, 8); sc0 += __shfl_xor(sc0, 2, 8); sc0 += __shfl_xor(sc0, 1, 8);
        sc1 += __shfl_xor(sc1, 4, 8); sc1 += __shfl_xor(sc1, 2, 8); sc1 += __shfl_xor(sc1, 1, 8);
        sc2 += __shfl_xor(sc2, 4, 8); sc2 += __shfl_xor(sc2, 2, 8); sc2 += __shfl_xor(sc2, 1, 8);
        sc3 += __shfl_xor(sc3, 4, 8); sc3 += __shfl_xor(sc3, 2, 8); sc3 += __shfl_xor(sc3, 1, 8);

        if (sub == 0) {
            *(float4*)(out + e0) = make_float4(sc0 + bias2, sc1 + bias2,
                                               sc2 + bias2, sc3 + bias2);
        }
    } else {
        for (int e = e0; e < n_edges; ++e) {
            const int s = src[e];
            const int d = dst[e];
            const uint4 pv = *(const uint4*)(P + (size_t)s * HF + j0);
            const uint4 qv = *(const uint4*)(Q + (size_t)d * HF + j0);
            float sc = dot8_relu(pv, qv, w2a, w2b);
            sc += __shfl_xor(sc, 4, 8); sc += __shfl_xor(sc, 2, 8); sc += __shfl_xor(sc, 1, 8);
            if (sub == 0) out[e] = sc + bias2;
        }
    }
}

extern "C" void kernel_launch(void* const* d_in, const int* in_sizes, int n_in,
                              void* d_out, int out_size, void* d_ws, size_t ws_size,
                              hipStream_t stream) {
    const float* h   = (const float*)d_in[0];
    const int*   src = (const int*)d_in[1];
    const int*   dst = (const int*)d_in[2];
    const float* W1  = (const float*)d_in[3];
    const float* b1  = (const float*)d_in[4];
    const float* W2  = (const float*)d_in[5];
    const float* b2  = (const float*)d_in[6];
    float* out = (float*)d_out;

    const int n_nodes = in_sizes[0] / HF;
    const int n_edges = in_sizes[1];

    __half* P = (__half*)d_ws;
    __half* Q = P + (size_t)n_nodes * HF;

    const int nblocks1 = (n_nodes + 63) / 64;            // 64 nodes per block
    node_proj_kernel<<<nblocks1, 256, 0, stream>>>(h, W1, b1, P, Q, n_nodes);

    const int ngroups  = (n_edges + 3) / 4;              // 4 edges per 8-lane group
    const int nblocks2 = (ngroups + 31) / 32;            // 32 groups per block
    edge_score_kernel<<<nblocks2, 256, 0, stream>>>(P, Q, src, dst, W2, b2, out, n_edges);
}

// Round 4
// 166.106 us; speedup vs baseline: 1.1601x; 1.0348x over previous
//
#include <hip/hip_runtime.h>
#include <hip/hip_fp16.h>

// score[e] = relu(h[src[e]]@W1s + h[dst[e]]@W1d + b1) @ W2 + b2
// N_NODES=100000, N_EDGES=1600000, H=64.
// Phase 1: per-node P = h@W1s + b1, Q = h@W1d (fp16, 25.6 MB, L2/L3-resident).
//   lane = node; each wave owns a 16-col strip of W1; W read via wave-uniform
//   scalar loads (SMEM, sK$-resident) -> zero LDS traffic, FMA-bound.
// Phase 2: per-edge gather P[src],Q[dst] + relu + dot(w2).
//   8-lane group per 8 edges -> 16 independent 16B gathers in flight.

#define HF 64

// ---------------- Phase 1: per-node projection ----------------
__global__ __launch_bounds__(512) void node_proj_kernel(
    const float* __restrict__ h, const float* __restrict__ W1,
    const float* __restrict__ b1, __half* __restrict__ P,
    __half* __restrict__ Q, int n_nodes)
{
    const int lane = threadIdx.x & 63;
    // wave id, forced wave-uniform so W addresses scalarize to s_load
    const int wave = __builtin_amdgcn_readfirstlane(threadIdx.x >> 6);
    const int c0   = wave * 16;        // column strip in [0,128)
    const bool isQ = c0 >= 64;
    const int ccol = c0 & 63;

    // W strip base: element (k, ccol+j) of this half at wbase[k*64 + j]
    const float* wbase = W1 + (isQ ? (64 * 64) : 0) + ccol;
    __half* const outh = (isQ ? Q : P) + ccol;

    const int n = blockIdx.x * 64 + lane;
    const bool valid = (n < n_nodes);
    const int nc = valid ? n : (n_nodes - 1);
    const float4* hrow = (const float4*)(h + (size_t)nc * HF);

    float acc[16];
    #pragma unroll
    for (int j = 0; j < 16; ++j) acc[j] = isQ ? 0.0f : b1[ccol + j];

    #pragma unroll
    for (int k4 = 0; k4 < 16; ++k4) {
        const float4 v = hrow[k4];
        const float* w0 = wbase + (k4 * 4 + 0) * 64;
        const float* w1 = wbase + (k4 * 4 + 1) * 64;
        const float* w2 = wbase + (k4 * 4 + 2) * 64;
        const float* w3 = wbase + (k4 * 4 + 3) * 64;
        #pragma unroll
        for (int j = 0; j < 16; ++j) {
            acc[j] = fmaf(v.x, w0[j], acc[j]);
            acc[j] = fmaf(v.y, w1[j], acc[j]);
            acc[j] = fmaf(v.z, w2[j], acc[j]);
            acc[j] = fmaf(v.w, w3[j], acc[j]);
        }
    }

    if (valid) {
        union { uint4 u[2]; __half2 hh[8]; } pk;
        #pragma unroll
        for (int j = 0; j < 8; ++j)
            pk.hh[j] = __floats2half2_rn(acc[j * 2], acc[j * 2 + 1]);
        __half* base = outh + (size_t)n * HF;
        *(uint4*)(base)     = pk.u[0];
        *(uint4*)(base + 8) = pk.u[1];
    }
}

// ---------------- Phase 2: per-edge score ----------------
__device__ __forceinline__ float dot8_relu(uint4 pv, uint4 qv, float4 wa, float4 wb) {
    const __half2* ph = (const __half2*)&pv;
    const __half2* qh = (const __half2*)&qv;
    const float2 p0 = __half22float2(ph[0]), q0 = __half22float2(qh[0]);
    const float2 p1 = __half22float2(ph[1]), q1 = __half22float2(qh[1]);
    const float2 p2 = __half22float2(ph[2]), q2 = __half22float2(qh[2]);
    const float2 p3 = __half22float2(ph[3]), q3 = __half22float2(qh[3]);
    float acc = 0.f;
    acc = fmaf(fmaxf(p0.x + q0.x, 0.f), wa.x, acc);
    acc = fmaf(fmaxf(p0.y + q0.y, 0.f), wa.y, acc);
    acc = fmaf(fmaxf(p1.x + q1.x, 0.f), wa.z, acc);
    acc = fmaf(fmaxf(p1.y + q1.y, 0.f), wa.w, acc);
    acc = fmaf(fmaxf(p2.x + q2.x, 0.f), wb.x, acc);
    acc = fmaf(fmaxf(p2.y + q2.y, 0.f), wb.y, acc);
    acc = fmaf(fmaxf(p3.x + q3.x, 0.f), wb.z, acc);
    acc = fmaf(fmaxf(p3.y + q3.y, 0.f), wb.w, acc);
    return acc;
}

__device__ __forceinline__ float red8(float v) {
    v += __shfl_xor(v, 4, 8);
    v += __shfl_xor(v, 2, 8);
    v += __shfl_xor(v, 1, 8);
    return v;
}

__global__ __launch_bounds__(256) void edge_score_kernel(
    const __half* __restrict__ P, const __half* __restrict__ Q,
    const int* __restrict__ src, const int* __restrict__ dst,
    const float* __restrict__ W2, const float* __restrict__ b2,
    float* __restrict__ out, int n_edges)
{
    const int tid   = blockIdx.x * 256 + threadIdx.x;
    const int sub   = threadIdx.x & 7;
    const int group = tid >> 3;
    const int j0    = sub * 8;
    const int e0    = group * 8;
    if (e0 >= n_edges) return;

    const float4 w2a = *(const float4*)(W2 + j0);
    const float4 w2b = *(const float4*)(W2 + j0 + 4);
    const float bias2 = b2[0];

    if (e0 + 8 <= n_edges) {
        const int4 sA = *(const int4*)(src + e0);
        const int4 sB = *(const int4*)(src + e0 + 4);
        const int4 dA = *(const int4*)(dst + e0);
        const int4 dB = *(const int4*)(dst + e0 + 4);

        const uint4 p0 = *(const uint4*)(P + (size_t)sA.x * HF + j0);
        const uint4 p1 = *(const uint4*)(P + (size_t)sA.y * HF + j0);
        const uint4 p2 = *(const uint4*)(P + (size_t)sA.z * HF + j0);
        const uint4 p3 = *(const uint4*)(P + (size_t)sA.w * HF + j0);
        const uint4 p4 = *(const uint4*)(P + (size_t)sB.x * HF + j0);
        const uint4 p5 = *(const uint4*)(P + (size_t)sB.y * HF + j0);
        const uint4 p6 = *(const uint4*)(P + (size_t)sB.z * HF + j0);
        const uint4 p7 = *(const uint4*)(P + (size_t)sB.w * HF + j0);
        const uint4 q0 = *(const uint4*)(Q + (size_t)dA.x * HF + j0);
        const uint4 q1 = *(const uint4*)(Q + (size_t)dA.y * HF + j0);
        const uint4 q2 = *(const uint4*)(Q + (size_t)dA.z * HF + j0);
        const uint4 q3 = *(const uint4*)(Q + (size_t)dA.w * HF + j0);
        const uint4 q4 = *(const uint4*)(Q + (size_t)dB.x * HF + j0);
        const uint4 q5 = *(const uint4*)(Q + (size_t)dB.y * HF + j0);
        const uint4 q6 = *(const uint4*)(Q + (size_t)dB.z * HF + j0);
        const uint4 q7 = *(const uint4*)(Q + (size_t)dB.w * HF + j0);

        float s0 = red8(dot8_relu(p0, q0, w2a, w2b));
        float s1 = red8(dot8_relu(p1, q1, w2a, w2b));
        float s2 = red8(dot8_relu(p2, q2, w2a, w2b));
        float s3 = red8(dot8_relu(p3, q3, w2a, w2b));
        float s4 = red8(dot8_relu(p4, q4, w2a, w2b));
        float s5 = red8(dot8_relu(p5, q5, w2a, w2b));
        float s6 = red8(dot8_relu(p6, q6, w2a, w2b));
        float s7 = red8(dot8_relu(p7, q7, w2a, w2b));

        if (sub == 0) {
            *(float4*)(out + e0)     = make_float4(s0 + bias2, s1 + bias2,
                                                   s2 + bias2, s3 + bias2);
            *(float4*)(out + e0 + 4) = make_float4(s4 + bias2, s5 + bias2,
                                                   s6 + bias2, s7 + bias2);
        }
    } else {
        for (int e = e0; e < n_edges; ++e) {
            const int s = src[e];
            const int d = dst[e];
            const uint4 pv = *(const uint4*)(P + (size_t)s * HF + j0);
            const uint4 qv = *(const uint4*)(Q + (size_t)d * HF + j0);
            float sc = red8(dot8_relu(pv, qv, w2a, w2b));
            if (sub == 0) out[e] = sc + bias2;
        }
    }
}

extern "C" void kernel_launch(void* const* d_in, const int* in_sizes, int n_in,
                              void* d_out, int out_size, void* d_ws, size_t ws_size,
                              hipStream_t stream) {
    const float* h   = (const float*)d_in[0];
    const int*   src = (const int*)d_in[1];
    const int*   dst = (const int*)d_in[2];
    const float* W1  = (const float*)d_in[3];
    const float* b1  = (const float*)d_in[4];
    const float* W2  = (const float*)d_in[5];
    const float* b2  = (const float*)d_in[6];
    float* out = (float*)d_out;

    const int n_nodes = in_sizes[0] / HF;
    const int n_edges = in_sizes[1];

    __half* P = (__half*)d_ws;
    __half* Q = P + (size_t)n_nodes * HF;

    const int nblocks1 = (n_nodes + 63) / 64;            // 64 nodes/block, 8 waves
    node_proj_kernel<<<nblocks1, 512, 0, stream>>>(h, W1, b1, P, Q, n_nodes);

    const int ngroups  = (n_edges + 7) / 8;              // 8 edges per 8-lane group
    const int nblocks2 = (ngroups + 31) / 32;            // 32 groups per 256-thr block
    edge_score_kernel<<<nblocks2, 256, 0, stream>>>(P, Q, src, dst, W2, b2, out, n_edges);
}

// Round 5
// 156.164 us; speedup vs baseline: 1.2340x; 1.0637x over previous
//
#include <hip/hip_runtime.h>
#include <hip/hip_fp16.h>

// score[e] = relu(h[src[e]]@W1s + h[dst[e]]@W1d + b1) @ W2 + b2
// N_NODES=100000, N_EDGES=1600000, H=64.
// Phase 1: per-node P = h@W1s + b1, Q = h@W1d (fp16, 25.6 MB, L2/L3-resident).
//   h tile staged in LDS via coalesced float4 loads (pad-65 rows: conflict-free
//   b32 reads); lane owns 2 nodes; W via wave-uniform (scalarizable) loads.
// Phase 2: per-edge gather P[src],Q[dst] + relu + dot(w2). At its random-gather
//   L2-miss floor (~3.6 TB/s, 57% L2 hit) — unchanged from R4.

#define HF  64
#define PAD 65
#define TN  128   // nodes per block tile

// ---------------- Phase 1: per-node projection ----------------
__global__ __launch_bounds__(512) void node_proj_kernel(
    const float* __restrict__ h, const float* __restrict__ W1,
    const float* __restrict__ b1, __half* __restrict__ P,
    __half* __restrict__ Q, int n_nodes)
{
    __shared__ float hs[TN * PAD];   // 128 * 65 * 4 = 33.28 KB

    const int tid  = threadIdx.x;
    const int lane = tid & 63;
    const int wave = __builtin_amdgcn_readfirstlane(tid >> 6);  // 0..7
    const int c0   = wave * 16;          // column strip in [0,128)
    const bool isQ = c0 >= 64;
    const int ccol = c0 & 63;

    const float* wbase = W1 + (isQ ? (HF * HF) : 0) + ccol;
    __half* const outh = (isQ ? Q : P) + ccol;

    const int n0 = blockIdx.x * TN;

    // ---- stage h[n0 : n0+TN][0:64] into LDS, coalesced ----
    {
        const int nrow  = (n_nodes - n0 < TN) ? (n_nodes - n0) : TN;  // >= 1
        const int maxf4 = nrow * 16;                                  // float4s
        const float4* hv = (const float4*)(h + (size_t)n0 * HF);
        #pragma unroll
        for (int it = 0; it < 4; ++it) {
            const int idx  = tid + it * 512;          // 0..2047
            const int cidx = (idx < maxf4) ? idx : 0; // clamp (tail block)
            const float4 v = hv[cidx];
            const int row = idx >> 4;
            const int c4  = (idx & 15) * 4;
            float* dst = &hs[row * PAD + c4];
            dst[0] = v.x; dst[1] = v.y; dst[2] = v.z; dst[3] = v.w;
        }
    }
    __syncthreads();

    // ---- compute: lane owns nodes n0+lane and n0+lane+64 ----
    float acc0[16], acc1[16];
    #pragma unroll
    for (int j = 0; j < 16; ++j) {
        const float b = isQ ? 0.0f : b1[ccol + j];
        acc0[j] = b; acc1[j] = b;
    }

    const float* r0 = &hs[lane * PAD];
    const float* r1 = &hs[(lane + 64) * PAD];

    #pragma unroll 4
    for (int k2 = 0; k2 < 32; ++k2) {
        const float a0 = r0[2 * k2], a1 = r0[2 * k2 + 1];
        const float c0v = r1[2 * k2], c1v = r1[2 * k2 + 1];
        const float* wA = wbase + (2 * k2) * HF;      // wave-uniform -> s_load
        const float* wB = wbase + (2 * k2 + 1) * HF;
        #pragma unroll
        for (int j = 0; j < 16; ++j) {
            const float wa = wA[j], wb = wB[j];
            acc0[j] = fmaf(a0, wa, acc0[j]);
            acc0[j] = fmaf(a1, wb, acc0[j]);
            acc1[j] = fmaf(c0v, wa, acc1[j]);
            acc1[j] = fmaf(c1v, wb, acc1[j]);
        }
    }

    const int n_a = n0 + lane;
    const int n_b = n0 + lane + 64;
    if (n_a < n_nodes) {
        union { uint4 u[2]; __half2 hh[8]; } pk;
        #pragma unroll
        for (int j = 0; j < 8; ++j)
            pk.hh[j] = __floats2half2_rn(acc0[2 * j], acc0[2 * j + 1]);
        __half* base = outh + (size_t)n_a * HF;
        *(uint4*)(base)     = pk.u[0];
        *(uint4*)(base + 8) = pk.u[1];
    }
    if (n_b < n_nodes) {
        union { uint4 u[2]; __half2 hh[8]; } pk;
        #pragma unroll
        for (int j = 0; j < 8; ++j)
            pk.hh[j] = __floats2half2_rn(acc1[2 * j], acc1[2 * j + 1]);
        __half* base = outh + (size_t)n_b * HF;
        *(uint4*)(base)     = pk.u[0];
        *(uint4*)(base + 8) = pk.u[1];
    }
}

// ---------------- Phase 2: per-edge score (unchanged, at gather floor) ----
__device__ __forceinline__ float dot8_relu(uint4 pv, uint4 qv, float4 wa, float4 wb) {
    const __half2* ph = (const __half2*)&pv;
    const __half2* qh = (const __half2*)&qv;
    const float2 p0 = __half22float2(ph[0]), q0 = __half22float2(qh[0]);
    const float2 p1 = __half22float2(ph[1]), q1 = __half22float2(qh[1]);
    const float2 p2 = __half22float2(ph[2]), q2 = __half22float2(qh[2]);
    const float2 p3 = __half22float2(ph[3]), q3 = __half22float2(qh[3]);
    float acc = 0.f;
    acc = fmaf(fmaxf(p0.x + q0.x, 0.f), wa.x, acc);
    acc = fmaf(fmaxf(p0.y + q0.y, 0.f), wa.y, acc);
    acc = fmaf(fmaxf(p1.x + q1.x, 0.f), wa.z, acc);
    acc = fmaf(fmaxf(p1.y + q1.y, 0.f), wa.w, acc);
    acc = fmaf(fmaxf(p2.x + q2.x, 0.f), wb.x, acc);
    acc = fmaf(fmaxf(p2.y + q2.y, 0.f), wb.y, acc);
    acc = fmaf(fmaxf(p3.x + q3.x, 0.f), wb.z, acc);
    acc = fmaf(fmaxf(p3.y + q3.y, 0.f), wb.w, acc);
    return acc;
}

__device__ __forceinline__ float red8(float v) {
    v += __shfl_xor(v, 4, 8);
    v += __shfl_xor(v, 2, 8);
    v += __shfl_xor(v, 1, 8);
    return v;
}

__global__ __launch_bounds__(256) void edge_score_kernel(
    const __half* __restrict__ P, const __half* __restrict__ Q,
    const int* __restrict__ src, const int* __restrict__ dst,
    const float* __restrict__ W2, const float* __restrict__ b2,
    float* __restrict__ out, int n_edges)
{
    const int tid   = blockIdx.x * 256 + threadIdx.x;
    const int sub   = threadIdx.x & 7;
    const int group = tid >> 3;
    const int j0    = sub * 8;
    const int e0    = group * 8;
    if (e0 >= n_edges) return;

    const float4 w2a = *(const float4*)(W2 + j0);
    const float4 w2b = *(const float4*)(W2 + j0 + 4);
    const float bias2 = b2[0];

    if (e0 + 8 <= n_edges) {
        const int4 sA = *(const int4*)(src + e0);
        const int4 sB = *(const int4*)(src + e0 + 4);
        const int4 dA = *(const int4*)(dst + e0);
        const int4 dB = *(const int4*)(dst + e0 + 4);

        const uint4 p0 = *(const uint4*)(P + (size_t)sA.x * HF + j0);
        const uint4 p1 = *(const uint4*)(P + (size_t)sA.y * HF + j0);
        const uint4 p2 = *(const uint4*)(P + (size_t)sA.z * HF + j0);
        const uint4 p3 = *(const uint4*)(P + (size_t)sA.w * HF + j0);
        const uint4 p4 = *(const uint4*)(P + (size_t)sB.x * HF + j0);
        const uint4 p5 = *(const uint4*)(P + (size_t)sB.y * HF + j0);
        const uint4 p6 = *(const uint4*)(P + (size_t)sB.z * HF + j0);
        const uint4 p7 = *(const uint4*)(P + (size_t)sB.w * HF + j0);
        const uint4 q0 = *(const uint4*)(Q + (size_t)dA.x * HF + j0);
        const uint4 q1 = *(const uint4*)(Q + (size_t)dA.y * HF + j0);
        const uint4 q2 = *(const uint4*)(Q + (size_t)dA.z * HF + j0);
        const uint4 q3 = *(const uint4*)(Q + (size_t)dA.w * HF + j0);
        const uint4 q4 = *(const uint4*)(Q + (size_t)dB.x * HF + j0);
        const uint4 q5 = *(const uint4*)(Q + (size_t)dB.y * HF + j0);
        const uint4 q6 = *(const uint4*)(Q + (size_t)dB.z * HF + j0);
        const uint4 q7 = *(const uint4*)(Q + (size_t)dB.w * HF + j0);

        float s0 = red8(dot8_relu(p0, q0, w2a, w2b));
        float s1 = red8(dot8_relu(p1, q1, w2a, w2b));
        float s2 = red8(dot8_relu(p2, q2, w2a, w2b));
        float s3 = red8(dot8_relu(p3, q3, w2a, w2b));
        float s4 = red8(dot8_relu(p4, q4, w2a, w2b));
        float s5 = red8(dot8_relu(p5, q5, w2a, w2b));
        float s6 = red8(dot8_relu(p6, q6, w2a, w2b));
        float s7 = red8(dot8_relu(p7, q7, w2a, w2b));

        if (sub == 0) {
            *(float4*)(out + e0)     = make_float4(s0 + bias2, s1 + bias2,
                                                   s2 + bias2, s3 + bias2);
            *(float4*)(out + e0 + 4) = make_float4(s4 + bias2, s5 + bias2,
                                                   s6 + bias2, s7 + bias2);
        }
    } else {
        for (int e = e0; e < n_edges; ++e) {
            const int s = src[e];
            const int d = dst[e];
            const uint4 pv = *(const uint4*)(P + (size_t)s * HF + j0);
            const uint4 qv = *(const uint4*)(Q + (size_t)d * HF + j0);
            float sc = red8(dot8_relu(pv, qv, w2a, w2b));
            if (sub == 0) out[e] = sc + bias2;
        }
    }
}

extern "C" void kernel_launch(void* const* d_in, const int* in_sizes, int n_in,
                              void* d_out, int out_size, void* d_ws, size_t ws_size,
                              hipStream_t stream) {
    const float* h   = (const float*)d_in[0];
    const int*   src = (const int*)d_in[1];
    const int*   dst = (const int*)d_in[2];
    const float* W1  = (const float*)d_in[3];
    const float* b1  = (const float*)d_in[4];
    const float* W2  = (const float*)d_in[5];
    const float* b2  = (const float*)d_in[6];
    float* out = (float*)d_out;

    const int n_nodes = in_sizes[0] / HF;
    const int n_edges = in_sizes[1];

    __half* P = (__half*)d_ws;
    __half* Q = P + (size_t)n_nodes * HF;

    const int nblocks1 = (n_nodes + TN - 1) / TN;        // 128 nodes/block
    node_proj_kernel<<<nblocks1, 512, 0, stream>>>(h, W1, b1, P, Q, n_nodes);

    const int ngroups  = (n_edges + 7) / 8;              // 8 edges per 8-lane group
    const int nblocks2 = (ngroups + 31) / 32;            // 32 groups per 256-thr block
    edge_score_kernel<<<nblocks2, 256, 0, stream>>>(P, Q, src, dst, W2, b2, out, n_edges);
}